// Round 17
// baseline (45.473 us; speedup 1.0000x reference)
//
#include <hip/hip_runtime.h>

#define B 64
#define T 512
#define E 512
#define H 64
#define NEG_INF (-1e30f)

// ---------------- projection GEMM params ----------------
#define PBM 64
#define PBK 64
#define PN 192
#define NCHK (E / PBK)

// q pre-scale: H^-0.5 * log2(e)  (scores land in log2 domain)
#define QSCALE 0.18033688011112043f
#define DEFER_THR 8.0f

using short8 = __attribute__((ext_vector_type(8))) short;
using f32x16 = __attribute__((ext_vector_type(16))) float;

__device__ __forceinline__ unsigned short f2bf(float f) {
    unsigned int u = __float_as_uint(f);
    u += 0x7fffu + ((u >> 16) & 1u);
    return (unsigned short)(u >> 16);
}
__device__ __forceinline__ unsigned int bfpack_tr(float lo, float hi) {
    return (__float_as_uint(hi) & 0xffff0000u) | (__float_as_uint(lo) >> 16);
}
__device__ __forceinline__ void async_copy16(const void* g, void* l) {
    __builtin_amdgcn_global_load_lds(
        (const __attribute__((address_space(1))) unsigned int*)g,
        (__attribute__((address_space(3))) unsigned int*)l, 16, 0, 0);
}

// counted waits (rule #18: sched_barrier after inline-asm waitcnt)
#define WAIT_VM16() do { asm volatile("s_waitcnt vmcnt(16)" ::: "memory"); \
                         __builtin_amdgcn_sched_barrier(0); } while (0)
#define WAIT_VM0()  do { asm volatile("s_waitcnt vmcnt(0)"  ::: "memory"); \
                         __builtin_amdgcn_sched_barrier(0); } while (0)
#define LGKM_BARRIER() do { asm volatile("s_waitcnt lgkmcnt(0)" ::: "memory"); \
                            __builtin_amdgcn_s_barrier(); \
                            __builtin_amdgcn_sched_barrier(0); } while (0)

// ---------------------------------------------------------------------------
// Kernel 0: one-time prep (unchanged).
// ---------------------------------------------------------------------------
__global__ __launch_bounds__(256) void prep(
    const float* __restrict__ Wq, const float* __restrict__ Wk,
    const float* __restrict__ Wv, const int* __restrict__ am,
    unsigned short* __restrict__ WT_swz, unsigned int* __restrict__ mbits)
{
    const int bid = blockIdx.x;
    if (bid < 384) {
        const int i = bid * 256 + threadIdx.x;
        const int c   = i / (PN * 64);
        const int rem = i - c * (PN * 64);
        const int row = rem >> 6;
        const int s   = rem & 63;
        const int klocal = s ^ ((row & 7) << 3);
        const int k   = c * 64 + klocal;
        const int seg = row >> 6, hh = row & 63;
        const float* W = (seg == 0) ? Wq : (seg == 1) ? Wk : Wv;
        WT_swz[i] = f2bf(W[(size_t)k * H + hh]);
    } else {
        const int i = (bid - 384) * 256 + threadIdx.x;
        const unsigned long long bal = __ballot(am[i] != 0);
        const int lane = threadIdx.x & 63;
        if (lane == 0)       mbits[i >> 5] = (unsigned int)bal;
        else if (lane == 32) mbits[i >> 5] = (unsigned int)(bal >> 32);
    }
}

// ---------------------------------------------------------------------------
// Kernel 1: projection GEMM with barrier-drain-free K-loop (R13, unchanged).
// ---------------------------------------------------------------------------
__global__ __launch_bounds__(256) void proj_gemm(
    const float* __restrict__ x,
    const unsigned short* __restrict__ WT_swz,
    unsigned short* __restrict__ qfrag, unsigned short* __restrict__ kfrag,
    unsigned short* __restrict__ vfrag)
{
    __shared__ unsigned short Xs[2][PBM * 64];
    __shared__ unsigned short Ws[2][PN * 64];

    const int tid  = threadIdx.x;
    const int wid  = tid >> 6;
    const int lane = tid & 63;
    const int hi   = lane >> 5;
    const int r    = lane & 31;
    const int row0 = blockIdx.x * PBM;

    const int mrow  = (wid >> 1) * 32 + r;
    const int hhalf = wid & 1;
    const int cbase = hhalf * 96;

    const int aBase = mrow * 128;
    const int aXor  = (mrow & 7) << 4;
    int bBase[3], bXor[3];
    #pragma unroll
    for (int nt = 0; nt < 3; ++nt) {
        const int col = cbase + nt * 32 + r;
        bBase[nt] = col * 128;
        bXor[nt]  = (col & 7) << 4;
    }
    const int xs_rr[2]  = { tid >> 3, (256 + tid) >> 3 };
    const int xs_s16    = tid & 7;

    const unsigned short* wsrcbase = WT_swz + hhalf * 6144 + lane * 8;
    const int wdst = hhalf * 12288;

    f32x16 acc[3] = {};
    float4 xA[2][2], xB[2][2];

    {
        #pragma unroll
        for (int p = 0; p < 12; ++p)
            async_copy16(wsrcbase + p * 512,
                         (char*)(&Ws[0][0]) + wdst + p * 1024);
        #pragma unroll
        for (int p = 0; p < 2; ++p) {
            const float4* src = reinterpret_cast<const float4*>(
                &x[(size_t)(row0 + xs_rr[p]) * E + xs_s16 * 8]);
            const float4 a0 = src[0], a1 = src[1];
            union { unsigned short us[8]; short8 v; } pk;
            pk.us[0] = f2bf(a0.x); pk.us[1] = f2bf(a0.y);
            pk.us[2] = f2bf(a0.z); pk.us[3] = f2bf(a0.w);
            pk.us[4] = f2bf(a1.x); pk.us[5] = f2bf(a1.y);
            pk.us[6] = f2bf(a1.z); pk.us[7] = f2bf(a1.w);
            const int cb = (xs_s16 * 16) ^ ((xs_rr[p] & 7) << 4);
            *reinterpret_cast<short8*>((char*)(&Xs[0][0]) + xs_rr[p] * 128 + cb) = pk.v;
        }
        #pragma unroll
        for (int p = 0; p < 2; ++p) {
            const float4* src = reinterpret_cast<const float4*>(
                &x[(size_t)(row0 + xs_rr[p]) * E + PBK + xs_s16 * 8]);
            xA[1][p] = src[0];
            xB[1][p] = src[1];
        }
        LGKM_BARRIER();
    }

    #pragma unroll
    for (int c = 0; c < NCHK; ++c) {
        const int cur = c & 1;

        if (c + 1 < NCHK) {
            const unsigned short* gw = wsrcbase + (size_t)(c + 1) * (PN * 64);
            #pragma unroll
            for (int p = 0; p < 12; ++p)
                async_copy16(gw + p * 512,
                             (char*)(&Ws[cur ^ 1][0]) + wdst + p * 1024);
        }
        if (c + 2 < NCHK) {
            const int kc = (c + 2) * PBK;
            #pragma unroll
            for (int p = 0; p < 2; ++p) {
                const float4* src = reinterpret_cast<const float4*>(
                    &x[(size_t)(row0 + xs_rr[p]) * E + kc + xs_s16 * 8]);
                xA[cur][p] = src[0];
                xB[cur][p] = src[1];
            }
        }

        if (c == NCHK - 1) { WAIT_VM0(); } else { WAIT_VM16(); }

        #pragma unroll
        for (int ks = 0; ks < 4; ++ks) {
            const int koff = ks * 32 + hi * 16;
            const short8 a = *reinterpret_cast<const short8*>(
                (const char*)(&Xs[cur][0]) + aBase + (koff ^ aXor));
            #pragma unroll
            for (int nt = 0; nt < 3; ++nt) {
                const short8 b = *reinterpret_cast<const short8*>(
                    (const char*)(&Ws[cur][0]) + bBase[nt] + (koff ^ bXor[nt]));
                acc[nt] = __builtin_amdgcn_mfma_f32_32x32x16_bf16(a, b, acc[nt], 0, 0, 0);
            }
        }

        if (c + 1 < NCHK) {
            const int nb = (c + 1) & 1;
            #pragma unroll
            for (int p = 0; p < 2; ++p) {
                union { unsigned short us[8]; short8 v; } pk;
                pk.us[0] = f2bf(xA[nb][p].x); pk.us[1] = f2bf(xA[nb][p].y);
                pk.us[2] = f2bf(xA[nb][p].z); pk.us[3] = f2bf(xA[nb][p].w);
                pk.us[4] = f2bf(xB[nb][p].x); pk.us[5] = f2bf(xB[nb][p].y);
                pk.us[6] = f2bf(xB[nb][p].z); pk.us[7] = f2bf(xB[nb][p].w);
                const int cb = (xs_s16 * 16) ^ ((xs_rr[p] & 7) << 4);
                *reinterpret_cast<short8*>(
                    (char*)(&Xs[cur ^ 1][0]) + xs_rr[p] * 128 + cb) = pk.v;
            }
            LGKM_BARRIER();
        }
    }

    #pragma unroll
    for (int nt = 0; nt < 3; ++nt) {
        const int gc  = cbase + nt * 32 + r;
        const int seg = gc >> 6;
        const int h   = gc & 63;
        #pragma unroll
        for (int reg = 0; reg < 16; ++reg) {
            const int drow = (reg & 3) + 8 * (reg >> 2) + 4 * hi;
            const int grow = row0 + (wid >> 1) * 32 + drow;
            const float val = acc[nt][reg];
            const int bb  = grow >> 9;
            const int key = grow & 511;
            const int blk = key >> 5;
            const int kk  = key & 31;
            if (seg == 0) {
                qfrag[(((size_t)bb * 16 + blk) * 4 + (h >> 4)) * 512
                      + (((h >> 3) & 1) * 32 + kk) * 8 + (h & 7)] = f2bf(val * QSCALE);
            } else if (seg == 1) {
                kfrag[(((size_t)bb * 16 + blk) * 4 + (h >> 4)) * 512
                      + (((h >> 3) & 1) * 32 + kk) * 8 + (h & 7)] = f2bf(val);
            } else {
                vfrag[(((size_t)bb * 16 + blk) * 4 + ((kk >> 4) * 2 + (h >> 5))) * 512
                      + (((kk >> 3) & 1) * 32 + (h & 31)) * 8 + (kk & 7)] = f2bf(val);
            }
        }
    }
}

// ---------------------------------------------------------------------------
// Kernel 2: flash attention, intra-block split-K.  Cross-lane ops REVERTED
// to the R13-proven __shfl_xor forms (permlane experiment dead after two
// failed conventions).  s_setprio around MFMA clusters retained (hint-only).
// ---------------------------------------------------------------------------
__global__ __launch_bounds__(256) void attn_online(
    const unsigned short* __restrict__ qfrag,
    const unsigned short* __restrict__ kfrag,
    const unsigned short* __restrict__ vfrag,
    const unsigned int* __restrict__ mbits,
    float* __restrict__ out)
{
    __shared__ float mlS[4][2][32];
    __shared__ float Ob[4][32][68];

    const int tid  = threadIdx.x;
    const int w    = tid >> 6;
    const int lane = tid & 63;
    const int hi = lane >> 5, r = lane & 31;
    const int h4 = 4 * hi;

    const int bid = blockIdx.x;
    const int kk2 = bid >> 3;
    const int b   = ((kk2 >> 4) << 3) | (bid & 7);
    const int s   = 15 - (kk2 & 15);
    const int t0  = s * 32;
    const int tq  = t0 + r;
    const int l8  = lane * 8;

    f32x16 accO[2] = {};
    float m = -INFINITY, l = 0.f;

    if (w <= s) {
        short8 qf[4];
        {
            const unsigned short* qb = qfrag + (((size_t)b * 16 + s) * 4) * 512;
            #pragma unroll
            for (int ks = 0; ks < 4; ++ks)
                qf[ks] = *reinterpret_cast<const short8*>(qb + ks * 512 + l8);
        }
        short8 kf[4], vb[4];
        {
            const unsigned short* kb = kfrag + (((size_t)b * 16 + w) * 4) * 512;
            const unsigned short* vv = vfrag + (((size_t)b * 16 + w) * 4) * 512;
            #pragma unroll
            for (int ks = 0; ks < 4; ++ks) {
                kf[ks] = *reinterpret_cast<const short8*>(kb + ks * 512 + l8);
                vb[ks] = *reinterpret_cast<const short8*>(vv + ks * 512 + l8);
            }
        }

        for (int j = w; j <= s; j += 4) {
            short8 kn[4], vn[4];
            if (j + 4 <= s) {
                const unsigned short* kb = kfrag + (((size_t)b * 16 + j + 4) * 4) * 512;
                const unsigned short* vv = vfrag + (((size_t)b * 16 + j + 4) * 4) * 512;
                #pragma unroll
                for (int ks = 0; ks < 4; ++ks) {
                    kn[ks] = *reinterpret_cast<const short8*>(kb + ks * 512 + l8);
                    vn[ks] = *reinterpret_cast<const short8*>(vv + ks * 512 + l8);
                }
            }

            __builtin_amdgcn_s_setprio(1);
            f32x16 sc = {};
            #pragma unroll
            for (int ks = 0; ks < 4; ++ks)
                sc = __builtin_amdgcn_mfma_f32_32x32x16_bf16(kf[ks], qf[ks], sc, 0, 0, 0);
            __builtin_amdgcn_s_setprio(0);

            const unsigned int mw = mbits[b * 16 + j];
            const bool fullm = (mw == 0xffffffffu);
            float cmax = -INFINITY;
            if (j == s) {
                #pragma unroll
                for (int reg = 0; reg < 16; ++reg) {
                    const int cr = (reg & 3) + 8 * (reg >> 2) + h4;
                    float v = sc[reg];
                    const bool bad = (32 * j + cr > tq) || (!fullm && !((mw >> cr) & 1u));
                    v = bad ? NEG_INF : v;
                    sc[reg] = v;
                    cmax = fmaxf(cmax, v);
                }
            } else if (fullm) {
                #pragma unroll
                for (int reg = 0; reg < 16; ++reg)
                    cmax = fmaxf(cmax, sc[reg]);
            } else {
                #pragma unroll
                for (int reg = 0; reg < 16; ++reg) {
                    const int cr = (reg & 3) + 8 * (reg >> 2) + h4;
                    float v = sc[reg];
                    v = ((mw >> cr) & 1u) ? v : NEG_INF;
                    sc[reg] = v;
                    cmax = fmaxf(cmax, v);
                }
            }
            cmax = fmaxf(cmax, __shfl_xor(cmax, 32));        // R13-proven

            if (!__all(cmax <= m + DEFER_THR)) {
                const float m_new = fmaxf(m, cmax);
                const float scale = exp2f(m - m_new);
                f32x16 scf;
                #pragma unroll
                for (int reg = 0; reg < 16; ++reg)
                    scf[reg] = __shfl(scale, (reg & 3) + 8 * (reg >> 2) + h4);
                #pragma unroll
                for (int reg = 0; reg < 16; ++reg) {
                    accO[0][reg] *= scf[reg];
                    accO[1][reg] *= scf[reg];
                }
                l *= scale;
                m = m_new;
            }

            float csum = 0.f;
            #pragma unroll
            for (int reg = 0; reg < 16; ++reg) {
                const float p = exp2f(sc[reg] - m);
                sc[reg] = p;
                csum += p;
            }
            csum += __shfl_xor(csum, 32);                    // R13-proven
            l += csum;

            // P -> A-frags: R13-proven shfl_xor + select exchange
            unsigned int pk[8];
            #pragma unroll
            for (int jj = 0; jj < 8; ++jj)
                pk[jj] = bfpack_tr(sc[2 * jj], sc[2 * jj + 1]);
            __builtin_amdgcn_s_setprio(1);
            #pragma unroll
            for (int hs = 0; hs < 2; ++hs) {
                const unsigned int p01 = pk[hs * 4 + 0], p23 = pk[hs * 4 + 1];
                const unsigned int p45 = pk[hs * 4 + 2], p67 = pk[hs * 4 + 3];
                const unsigned int sendA = hi ? p01 : p45;
                const unsigned int sendB = hi ? p23 : p67;
                const unsigned int recvA = (unsigned int)__shfl_xor((int)sendA, 32);
                const unsigned int recvB = (unsigned int)__shfl_xor((int)sendB, 32);
                union { unsigned int uu[4]; short8 s8; } aw;
                aw.uu[0] = hi ? recvA : p01;
                aw.uu[1] = hi ? recvB : p23;
                aw.uu[2] = hi ? p45 : recvA;
                aw.uu[3] = hi ? p67 : recvB;
                #pragma unroll
                for (int tile = 0; tile < 2; ++tile)
                    accO[tile] = __builtin_amdgcn_mfma_f32_32x32x16_bf16(
                        aw.s8, vb[hs * 2 + tile], accO[tile], 0, 0, 0);
            }
            __builtin_amdgcn_s_setprio(0);

            #pragma unroll
            for (int ks = 0; ks < 4; ++ks) { kf[ks] = kn[ks]; vb[ks] = vn[ks]; }
        }
    }

    if (hi == 0) { mlS[w][0][r] = m; mlS[w][1][r] = l; }
    #pragma unroll
    for (int reg = 0; reg < 16; ++reg) {
        const int qrow = (reg & 3) + 8 * (reg >> 2) + h4;
        Ob[w][qrow][r]      = accO[0][reg];
        Ob[w][qrow][r + 32] = accO[1][reg];
    }
    __syncthreads();

    {
        const int row = tid >> 3;
        const int c8  = (tid & 7) * 8;

        float mi[4], li[4];
        float mstar = -INFINITY;
        #pragma unroll
        for (int w2 = 0; w2 < 4; ++w2) {
            mi[w2] = mlS[w2][0][row];
            li[w2] = mlS[w2][1][row];
            mstar = fmaxf(mstar, mi[w2]);
        }
        float L = 0.f, fw[4];
        #pragma unroll
        for (int w2 = 0; w2 < 4; ++w2) {
            fw[w2] = exp2f(mi[w2] - mstar);
            L += fw[w2] * li[w2];
        }
        const float inv = 1.f / L;

        float acc[8] = {};
        #pragma unroll
        for (int w2 = 0; w2 < 4; ++w2) {
            const float4 lo = *reinterpret_cast<const float4*>(&Ob[w2][row][c8]);
            const float4 hi4v = *reinterpret_cast<const float4*>(&Ob[w2][row][c8 + 4]);
            acc[0] += fw[w2] * lo.x;  acc[1] += fw[w2] * lo.y;
            acc[2] += fw[w2] * lo.z;  acc[3] += fw[w2] * lo.w;
            acc[4] += fw[w2] * hi4v.x; acc[5] += fw[w2] * hi4v.y;
            acc[6] += fw[w2] * hi4v.z; acc[7] += fw[w2] * hi4v.w;
        }

        float* op = &out[((size_t)b * T + t0 + row) * H + c8];
        float4 o0 = { acc[0] * inv, acc[1] * inv, acc[2] * inv, acc[3] * inv };
        float4 o1 = { acc[4] * inv, acc[5] * inv, acc[6] * inv, acc[7] * inv };
        *reinterpret_cast<float4*>(op)     = o0;
        *reinterpret_cast<float4*>(op + 4) = o1;
    }
}

// ---------------------------------------------------------------------------
extern "C" void kernel_launch(void* const* d_in, const int* in_sizes, int n_in,
                              void* d_out, int out_size, void* d_ws, size_t ws_size,
                              hipStream_t stream) {
    const float* x         = (const float*)d_in[0];
    const int*   attn_mask = (const int*)d_in[1];
    const float* Wk        = (const float*)d_in[2];
    const float* Wq        = (const float*)d_in[3];
    const float* Wv        = (const float*)d_in[4];
    float* out = (float*)d_out;

    unsigned short* qfrag  = (unsigned short*)d_ws;                      // 4 MB
    unsigned short* kfrag  = qfrag + (size_t)B * T * H;                  // 4 MB
    unsigned short* vfrag  = kfrag + (size_t)B * T * H;                  // 4 MB
    unsigned short* WT_swz = vfrag + (size_t)B * T * H;                  // 192 KB
    unsigned int*   mbits  = (unsigned int*)(WT_swz + (size_t)PN * E);   // 4 KB

    prep<<<512, 256, 0, stream>>>(Wq, Wk, Wv, attn_mask, WT_swz, mbits);
    proj_gemm<<<(B * T) / PBM, 256, 0, stream>>>(x, WT_swz, qfrag, kfrag, vfrag);
    attn_online<<<B * 16, 256, 0, stream>>>(qfrag, kfrag, vfrag, mbits, out);
}